// Round 4
// baseline (626.245 us; speedup 1.0000x reference)
//
#include <hip/hip_runtime.h>
#include <hip/hip_bf16.h>
#include <math.h>

#define B_  2
#define S_  2048
#define H_  2048
#define NH_ 16
#define HD_ 128
#define M_  (B_*S_)   // 4096

typedef __bf16 bf16_t;
typedef _Float16 f16_t;
typedef __bf16 bf16x8 __attribute__((ext_vector_type(8)));
typedef __bf16 bf16x4 __attribute__((ext_vector_type(4)));
typedef _Float16 f16x4 __attribute__((ext_vector_type(4)));
typedef float  f32x4  __attribute__((ext_vector_type(4)));

__device__ __forceinline__ f32x4 mfma_bf16_32(bf16x8 a, bf16x8 b, f32x4 c) {
  return __builtin_amdgcn_mfma_f32_16x16x32_bf16(a, b, c, 0, 0, 0);
}
__device__ __forceinline__ f32x4 mfma_f16_16(f16x4 a, f16x4 b, f32x4 c) {
  return __builtin_amdgcn_mfma_f32_16x16x16f16(a, b, c, 0, 0, 0);
}
__device__ __forceinline__ void gl_lds16(const void* g, void* l) {
  __builtin_amdgcn_global_load_lds((const __attribute__((address_space(1))) void*)g,
                                   (__attribute__((address_space(3))) void*)l, 16, 0, 0);
}
// s_waitcnt simm16 (gfx9): vmcnt[3:0] | expcnt(7=nowait)<<4 | lgkmcnt(15=nowait)<<8 | vmcnt[5:4]<<14
#define WAITCNT_VM(n) { asm volatile("" ::: "memory"); \
                        __builtin_amdgcn_s_waitcnt(((n) & 0xF) | 0x70 | 0xF00 | (((n) >> 4) << 14)); \
                        asm volatile("" ::: "memory"); }
#define BARRIER()     { asm volatile("" ::: "memory"); __builtin_amdgcn_s_barrier(); \
                        asm volatile("" ::: "memory"); }

// ---------------- all fp32 -> bf16 converts in one launch ----------------
__global__ void cvt_all(const float* __restrict__ hs, const float* __restrict__ wq,
                        const float* __restrict__ wk, const float* __restrict__ wv,
                        const float* __restrict__ wo, bf16_t* __restrict__ hs_b,
                        bf16_t* __restrict__ wqkv, bf16_t* __restrict__ wo_b) {
  int i = (blockIdx.x * 256 + threadIdx.x) * 4;   // element index (24M total)
  const float* src;
  bf16_t* dst;
  if (i < 8388608)        { src = hs + i;              dst = hs_b + i; }
  else if (i < 12582912)  { src = wq + (i - 8388608);  dst = wqkv + (i - 8388608); }
  else if (i < 16777216)  { src = wk + (i - 12582912); dst = wqkv + (i - 8388608); }
  else if (i < 20971520)  { src = wv + (i - 16777216); dst = wqkv + (i - 8388608); }
  else                    { src = wo + (i - 20971520); dst = wo_b + (i - 20971520); }
  float4 v = *(const float4*)src;
  bf16x4 o;
  o[0] = (bf16_t)v.x; o[1] = (bf16_t)v.y; o[2] = (bf16_t)v.z; o[3] = (bf16_t)v.w;
  *(bf16x4*)dst = o;
}

// ---------------- bf16 MFMA GEMM, global_load_lds + XOR-swizzled LDS ----------------
// MODE 0: fused QKV epilogue (N=6144): n<2048 -> Q [B,NH,S,HD] bf16,
//         n<4096 -> K same layout, else -> V DIRECT-PACKED PV-fragment layout f16:
//         Vp[((bh*32+kt)*32 + (hd>>4)*4 + ((s>>4)&3))*256 + lane*4 + (s&3)]
// MODE 1: fp32 row-major [M, H_]
// launch_bounds (256,5): LDS 32 KB allows 5 blocks/CU; r3 showed occupancy
// pinned at the declared value (33% @ 3) with VGPR=64 far under limit.
template<int MODE>
__global__ __launch_bounds__(256, 5)
void gemm_mfma(const bf16_t* __restrict__ A, const bf16_t* __restrict__ Bt,
               bf16_t* __restrict__ outQ, bf16_t* __restrict__ outK,
               f16_t* __restrict__ outV, float* __restrict__ outF, int K) {
  __shared__ bf16_t sA[128 * 64];   // 16 KB
  __shared__ bf16_t sB[128 * 64];
  const int tid  = threadIdx.x;
  const int lane = tid & 63;
  const int w    = tid >> 6;
  const int col  = lane & 15;
  const int quad = lane >> 4;
  const int w_m  = (w & 1) * 64;
  const int w_n  = (w >> 1) * 64;
  const int m_blk = blockIdx.y * 128;
  const int n_blk = blockIdx.x * 128;

  const int srow   = lane >> 3;
  const int schunk = (lane & 7) ^ (lane >> 3);   // XOR swizzle (row&7 == lane>>3)

  const bf16_t* Abase = A  + (size_t)m_blk * K;
  const bf16_t* Bbase = Bt + (size_t)n_blk * K;

  f32x4 acc[4][4] = {};

  for (int kk = 0; kk < K; kk += 64) {
    __syncthreads();
#pragma unroll
    for (int p = 0; p < 4; ++p) {
      int seg = w * 4 + p;
      int row = seg * 8 + srow;
      gl_lds16(Abase + (size_t)row * K + kk + schunk * 8, &sA[seg * 512]);
      gl_lds16(Bbase + (size_t)row * K + kk + schunk * 8, &sB[seg * 512]);
    }
    __syncthreads();
#pragma unroll
    for (int kc = 0; kc < 2; ++kc) {
      bf16x8 af[4], bfr[4];
      const int cs = (kc * 4 + quad) ^ (col & 7);
#pragma unroll
      for (int i = 0; i < 4; ++i) {
        af[i]  = *(const bf16x8*)&sA[(w_m + i * 16 + col) * 64 + cs * 8];
        bfr[i] = *(const bf16x8*)&sB[(w_n + i * 16 + col) * 64 + cs * 8];
      }
#pragma unroll
      for (int mi = 0; mi < 4; ++mi)
#pragma unroll
        for (int ni = 0; ni < 4; ++ni)
          acc[mi][ni] = mfma_bf16_32(af[mi], bfr[ni], acc[mi][ni]);
    }
  }

  const int sel = n_blk >> 11;   // block-uniform
  if (MODE == 0 && sel == 2) {
    // V: write packed PV fragments, one coalesced f16x4 store per (mi,ni)
#pragma unroll
    for (int mi = 0; mi < 4; ++mi)
#pragma unroll
      for (int ni = 0; ni < 4; ++ni) {
        int m0 = m_blk + w_m + mi * 16 + quad * 4;    // r=0 row
        int n  = n_blk + w_n + ni * 16 + col;
        int n_l = n & (H_ - 1);
        int head = n_l >> 7, hd = n_l & (HD_ - 1);
        int b = m0 >> 11, s0 = m0 & (S_ - 1);
        int bh = b * NH_ + head;
        int frag = (bh * 32 + (s0 >> 6)) * 32 + (hd >> 4) * 4 + ((s0 >> 4) & 3);
        int lane2 = ((s0 >> 2) & 3) * 16 + (hd & 15); // == quad*16+col
        f16x4 o;
#pragma unroll
        for (int r = 0; r < 4; ++r) o[r] = (f16_t)acc[mi][ni][r];
        *(f16x4*)&outV[(size_t)frag * 256 + lane2 * 4] = o;
      }
  } else {
#pragma unroll
    for (int mi = 0; mi < 4; ++mi)
#pragma unroll
      for (int ni = 0; ni < 4; ++ni)
#pragma unroll
        for (int r = 0; r < 4; ++r) {
          int m = m_blk + w_m + mi * 16 + quad * 4 + r;
          int n = n_blk + w_n + ni * 16 + col;
          float v = acc[mi][ni][r];
          if (MODE == 0) {
            int n_l = n & (H_ - 1);
            int head = n_l >> 7, hd = n_l & (HD_ - 1);
            int b = m >> 11, s = m & (S_ - 1);
            size_t idx = (((size_t)(b * NH_ + head)) * S_ + s) * HD_ + hd;
            if (sel == 0) outQ[idx] = (bf16_t)v;
            else          outK[idx] = (bf16_t)v;
          } else {
            outF[(size_t)m * H_ + n] = v;
          }
        }
  }
}

// ---------------- RoPE(Q in-place) + RoPE(K)+pack into MFMA A-fragment order ----
// Kp frag (bh, kt, t, kc): lane(col,quad) holds K[bh][kt*64+t*16+col][kc*32+quad*8..+7]
__global__ void rope_pack(bf16_t* __restrict__ Qb, const bf16_t* __restrict__ Kn,
                          bf16_t* __restrict__ Kp) {
  int i = blockIdx.x * 256 + threadIdx.x;   // 2 * 524288 threads
  int isK = i >> 19;
  int ii = i & 524287;
  int d8 = ii & 7;
  int s  = (ii >> 3) & (S_ - 1);
  int bh = ii >> 14;
  int d0 = d8 * 8;
  const bf16_t* row = (isK ? Kn : (const bf16_t*)Qb) + ((size_t)bh * S_ + s) * HD_;
  bf16x8 a = *(const bf16x8*)(row + d0);
  bf16x8 b = *(const bf16x8*)(row + d0 + 64);
  bf16x8 o1, o2;
#pragma unroll
  for (int j = 0; j < 8; ++j) {
    int d = d0 + j;
    float ang = (float)s * exp2f(-(float)d * (13.287712379549449f / 64.f));
    float c = cosf(ang), sn = sinf(ang);
    float x1 = (float)a[j], x2 = (float)b[j];
    o1[j] = (bf16_t)(x1 * c - x2 * sn);
    o2[j] = (bf16_t)(x2 * c + x1 * sn);
  }
  if (!isK) {
    bf16_t* wr = Qb + ((size_t)bh * S_ + s) * HD_;
    *(bf16x8*)(wr + d0)      = o1;
    *(bf16x8*)(wr + d0 + 64) = o2;
  } else {
    int kt = s >> 6, t = (s >> 4) & 3;
    int lane_ = (d8 & 3) * 16 + (s & 15);
    int kc1 = d0 >> 5;
    bf16_t* base = Kp + ((size_t)(bh * 32 + kt) * 16) * 512;
    *(bf16x8*)(base + (size_t)(t * 4 + kc1) * 512 + lane_ * 8)     = o1;
    *(bf16x8*)(base + (size_t)(t * 4 + kc1 + 2) * 512 + lane_ * 8) = o2;
  }
}

// ---------------- Flash causal attention: SINGLE-buffer K/V (32 KB LDS), 5 blk/CU --
// Per-tile split-wait pipeline:
//   QK(sK) | softmax | vmcnt(0) BAR(publish sV; sK dead) | stageK(kt+1) issued
//   PV(sV) | BAR | stageV(kt+1) issued, vmcnt(4)=K done (V crosses barrier in
//   flight) | BAR(publish sK).
// qt map: per-XCD balanced AND per-CU balanced (g2 rotation by y-octet).
// T13 defer-max (THR=8, log2 domain): skip the oacc rescale pass unless some
// row's max grew by >8; P values then bounded by 2^8=256 (safe in f16).
__global__ __launch_bounds__(256, 5)
void flash_attn(const bf16_t* __restrict__ Q, const bf16_t* __restrict__ Kp,
                const f16_t* __restrict__ Vp, bf16_t* __restrict__ Out) {
  __shared__ bf16_t sK[8192];   // 16 KB
  __shared__ f16_t  sV[8192];   // 16 KB
  const int lane = threadIdx.x & 63;
  const int col  = lane & 15;
  const int quad = lane >> 4;
  const int w    = threadIdx.x >> 6;

  const int c = blockIdx.x & 7, g = blockIdx.x >> 3;
  const int g2 = (g + (blockIdx.y >> 3)) & 3;
  const int qt = (g2 == 0) ? c : (g2 == 1) ? 15 - c : (g2 == 2) ? 16 + c : 31 - c;
  const int bh = blockIdx.y;
  const int ktmax = qt;

  const bf16_t* KpB = Kp + (size_t)bh * 32 * 8192;
  const f16_t*  VpB = Vp + (size_t)bh * 32 * 8192;

  auto stageK = [&](int kt) {
#pragma unroll
    for (int r = 0; r < 4; ++r) {
      int seg = r * 4 + w;
      gl_lds16(KpB + (size_t)kt * 8192 + seg * 512 + lane * 8, &sK[seg * 512]);
    }
  };
  auto stageV = [&](int kt) {
#pragma unroll
    for (int r = 0; r < 4; ++r) {
      int seg = r * 4 + w;
      gl_lds16(VpB + (size_t)kt * 8192 + seg * 512 + lane * 8, &sV[seg * 512]);
    }
  };

  // Q fragments (16 q-rows/wave), pre-scaled by 1/sqrt(HD)*log2(e).
  // These normal loads are fully retired (compiler waitcnt before the scale
  // loop) BEFORE any gl_lds16 issues, so manual vmcnt counting stays exact.
  const float scale2 = 0.12751744154f;
  const bf16_t* Qrow = Q + ((size_t)bh * S_ + qt * 64 + w * 16 + col) * HD_;
  bf16x8 qf[4];
#pragma unroll
  for (int kc = 0; kc < 4; ++kc) {
    qf[kc] = *(const bf16x8*)(Qrow + kc * 32 + quad * 8);
#pragma unroll
    for (int j = 0; j < 8; ++j) qf[kc][j] = (bf16_t)((float)qf[kc][j] * scale2);
  }

  f32x4 oacc[8] = {};
  float m_i = -1e30f, l_i = 0.f;

  stageK(0);            // 4 loads
  stageV(0);            // 4 loads
  WAITCNT_VM(4)         // K0 done; V0 stays in flight across the barrier
  BARRIER();

  for (int kt = 0; kt <= ktmax; ++kt) {
    // St = K.Q^T (C-layout: col=q, quad*4+r=k)
    f32x4 st[4] = {};
    __builtin_amdgcn_s_setprio(1);
#pragma unroll
    for (int kc = 0; kc < 4; ++kc)
#pragma unroll
      for (int t = 0; t < 4; ++t) {
        bf16x8 kf = *(const bf16x8*)&sK[(t * 4 + kc) * 512 + lane * 8];
        st[t] = mfma_bf16_32(kf, qf[kc], st[t]);
      }
    __builtin_amdgcn_s_setprio(0);

    if (kt == ktmax) {           // diagonal tile: causal mask
      int ql = w * 16 + col;
#pragma unroll
      for (int t = 0; t < 4; ++t)
#pragma unroll
        for (int r = 0; r < 4; ++r)
          if (t * 16 + quad * 4 + r > ql) st[t][r] = -1e30f;
    }

    // online softmax (log2 domain), in-register over 16 + shfl(16,32)
    float mx = st[0][0];
#pragma unroll
    for (int t = 0; t < 4; ++t)
#pragma unroll
      for (int r = 0; r < 4; ++r) mx = fmaxf(mx, st[t][r]);
    mx = fmaxf(mx, __shfl_xor(mx, 16, 64));
    mx = fmaxf(mx, __shfl_xor(mx, 32, 64));
    // T13 defer-max: only rescale when some row's max grew past THR=8.
    if (__ballot(mx - m_i > 8.0f)) {
      float mn = fmaxf(m_i, mx);
      float alpha = exp2f(m_i - mn);
#pragma unroll
      for (int dt = 0; dt < 8; ++dt)
#pragma unroll
        for (int r = 0; r < 4; ++r) oacc[dt][r] *= alpha;
      l_i *= alpha;
      m_i = mn;
    }

    float sum = 0.f;
    f16x4 pf[4];
#pragma unroll
    for (int t = 0; t < 4; ++t)
#pragma unroll
      for (int r = 0; r < 4; ++r) {
        float pv = exp2f(st[t][r] - m_i);
        sum += pv;
        pf[t][r] = (f16_t)pv;
      }
    sum += __shfl_xor(sum, 16, 64);
    sum += __shfl_xor(sum, 32, 64);
    l_i += sum;

    WAITCNT_VM(0)        // own V-stage loads done (all else long retired)
    BARRIER();           // publish sV; also: all waves finished reading sK

    if (kt < ktmax) stageK(kt + 1);   // into sK, hides under PV

    // O^T += V^T.P^T  (P straight from registers; V frags contiguous/lane)
    __builtin_amdgcn_s_setprio(1);
#pragma unroll
    for (int t = 0; t < 4; ++t)
#pragma unroll
      for (int dt = 0; dt < 8; ++dt) {
        f16x4 vf = *(const f16x4*)&sV[(dt * 4 + t) * 256 + lane * 4];
        oacc[dt] = mfma_f16_16(vf, pf[t], oacc[dt]);
      }
    __builtin_amdgcn_s_setprio(0);

    if (kt < ktmax) {
      BARRIER();         // all waves finished reading sV
      stageV(kt + 1);    // into sV
      WAITCNT_VM(4)      // K(kt+1) done; V(kt+1) crosses barrier in flight
      BARRIER();         // publish sK(kt+1)
    }
  }

  float inv = 1.0f / l_i;
  int b = bh >> 4, h = bh & (NH_ - 1);
  int qg = qt * 64 + w * 16 + col;
  bf16_t* Orow = Out + ((size_t)b * S_ + qg) * H_ + h * HD_;
#pragma unroll
  for (int dt = 0; dt < 8; ++dt) {
    bf16x4 o4;
#pragma unroll
    for (int r = 0; r < 4; ++r) o4[r] = (bf16_t)(oacc[dt][r] * inv);
    *(bf16x4*)(Orow + dt * 16 + quad * 4) = o4;
  }
}

// ---------------- launch ----------------
extern "C" void kernel_launch(void* const* d_in, const int* in_sizes, int n_in,
                              void* d_out, int out_size, void* d_ws, size_t ws_size,
                              hipStream_t stream) {
  const float* hs = (const float*)d_in[0];
  // d_in[1] = attention_mask: exactly causal tril(0,-1e9) -> applied analytically
  const float* Wq = (const float*)d_in[2];
  const float* Wk = (const float*)d_in[3];
  const float* Wv = (const float*)d_in[4];
  const float* Wo = (const float*)d_in[5];
  float* out = (float*)d_out;

  char* ws = (char*)d_ws;
  size_t off = 0;
  auto alloc = [&](size_t bytes) -> void* {
    void* p = ws + off;
    off += (bytes + 255) & ~(size_t)255;
    return p;
  };
  bf16_t* hs_b  = (bf16_t*)alloc((size_t)M_ * H_ * 2);
  bf16_t* wqkv  = (bf16_t*)alloc((size_t)3 * H_ * H_ * 2);   // reused as Kp after GEMM
  bf16_t* wo_b  = (bf16_t*)alloc((size_t)H_ * H_ * 2);
  bf16_t* Qbuf  = (bf16_t*)alloc((size_t)M_ * H_ * 2);
  bf16_t* Kbuf  = (bf16_t*)alloc((size_t)M_ * H_ * 2);
  f16_t*  Vp    = (f16_t*)alloc((size_t)M_ * H_ * 2);        // packed PV fragments
  bf16_t* attn  = (bf16_t*)alloc((size_t)M_ * H_ * 2);

  cvt_all<<<24576, 256, 0, stream>>>(hs, Wq, Wk, Wv, Wo, hs_b, wqkv, wo_b);

  // fused QKV projection; V epilogue writes packed Vp directly
  gemm_mfma<0><<<dim3(48, 32), 256, 0, stream>>>(hs_b, wqkv, Qbuf, Kbuf,
                                                 Vp, nullptr, H_);

  bf16_t* Kp = wqkv;   // wqkv dead after GEMM
  rope_pack<<<4096, 256, 0, stream>>>(Qbuf, Kbuf, Kp);

  flash_attn<<<dim3(32, 32), 256, 0, stream>>>(Qbuf, Kp, Vp, attn);

  gemm_mfma<1><<<dim3(16, 32), 256, 0, stream>>>(attn, wo_b, nullptr, nullptr,
                                                 nullptr, out, H_);
}

// Round 5
// 381.329 us; speedup vs baseline: 1.6423x; 1.6423x over previous
//
#include <hip/hip_runtime.h>
#include <hip/hip_bf16.h>
#include <math.h>

#define B_  2
#define S_  2048
#define H_  2048
#define NH_ 16
#define HD_ 128
#define M_  (B_*S_)   // 4096

typedef __bf16 bf16_t;
typedef _Float16 f16_t;
typedef __bf16 bf16x8 __attribute__((ext_vector_type(8)));
typedef __bf16 bf16x4 __attribute__((ext_vector_type(4)));
typedef _Float16 f16x4 __attribute__((ext_vector_type(4)));
typedef float  f32x4  __attribute__((ext_vector_type(4)));

__device__ __forceinline__ f32x4 mfma_bf16_32(bf16x8 a, bf16x8 b, f32x4 c) {
  return __builtin_amdgcn_mfma_f32_16x16x32_bf16(a, b, c, 0, 0, 0);
}
__device__ __forceinline__ f32x4 mfma_f16_16(f16x4 a, f16x4 b, f32x4 c) {
  return __builtin_amdgcn_mfma_f32_16x16x16f16(a, b, c, 0, 0, 0);
}
__device__ __forceinline__ void gl_lds16(const void* g, void* l) {
  __builtin_amdgcn_global_load_lds((const __attribute__((address_space(1))) void*)g,
                                   (__attribute__((address_space(3))) void*)l, 16, 0, 0);
}
// s_waitcnt simm16 (gfx9): vmcnt[3:0] | expcnt(7=nowait)<<4 | lgkmcnt(15=nowait)<<8 | vmcnt[5:4]<<14
#define WAITCNT_VM(n) { asm volatile("" ::: "memory"); \
                        __builtin_amdgcn_s_waitcnt(((n) & 0xF) | 0x70 | 0xF00 | (((n) >> 4) << 14)); \
                        asm volatile("" ::: "memory"); }
#define BARRIER()     { asm volatile("" ::: "memory"); __builtin_amdgcn_s_barrier(); \
                        asm volatile("" ::: "memory"); }

// ---------------- all fp32 -> bf16 converts in one launch ----------------
__global__ void cvt_all(const float* __restrict__ hs, const float* __restrict__ wq,
                        const float* __restrict__ wk, const float* __restrict__ wv,
                        const float* __restrict__ wo, bf16_t* __restrict__ hs_b,
                        bf16_t* __restrict__ wqkv, bf16_t* __restrict__ wo_b) {
  int i = (blockIdx.x * 256 + threadIdx.x) * 4;   // element index (24M total)
  const float* src;
  bf16_t* dst;
  if (i < 8388608)        { src = hs + i;              dst = hs_b + i; }
  else if (i < 12582912)  { src = wq + (i - 8388608);  dst = wqkv + (i - 8388608); }
  else if (i < 16777216)  { src = wk + (i - 12582912); dst = wqkv + (i - 8388608); }
  else if (i < 20971520)  { src = wv + (i - 16777216); dst = wqkv + (i - 8388608); }
  else                    { src = wo + (i - 20971520); dst = wo_b + (i - 20971520); }
  float4 v = *(const float4*)src;
  bf16x4 o;
  o[0] = (bf16_t)v.x; o[1] = (bf16_t)v.y; o[2] = (bf16_t)v.z; o[3] = (bf16_t)v.w;
  *(bf16x4*)dst = o;
}

// ---------------- bf16 MFMA GEMM, global_load_lds + XOR-swizzled LDS ----------------
// MODE 0: fused QKV epilogue (N=6144): n<2048 -> Q [B,NH,S,HD] bf16,
//         n<4096 -> K same layout, else -> V DIRECT-PACKED PV-fragment layout f16:
//         Vp[((bh*32+kt)*32 + (hd>>4)*4 + ((s>>4)&3))*256 + lane*4 + (s&3)]
// MODE 1: fp32 row-major [M, H_]
// launch_bounds (256,3): r4 falsified the "bound pins occupancy" theory —
// (256,5) forced the VGPR budget to ~96-102 while this kernel needs ~64 arch
// VGPR + 64 AGPR (unified file on gfx950) -> accumulator spill, WRITE_SIZE
// 49->664 MB, 3x slower. Keep the budget at 170 (3 waves/EU); HW residency
// follows actual VGPR/LDS anyway.
template<int MODE>
__global__ __launch_bounds__(256, 3)
void gemm_mfma(const bf16_t* __restrict__ A, const bf16_t* __restrict__ Bt,
               bf16_t* __restrict__ outQ, bf16_t* __restrict__ outK,
               f16_t* __restrict__ outV, float* __restrict__ outF, int K) {
  __shared__ bf16_t sA[128 * 64];   // 16 KB
  __shared__ bf16_t sB[128 * 64];
  const int tid  = threadIdx.x;
  const int lane = tid & 63;
  const int w    = tid >> 6;
  const int col  = lane & 15;
  const int quad = lane >> 4;
  const int w_m  = (w & 1) * 64;
  const int w_n  = (w >> 1) * 64;
  const int m_blk = blockIdx.y * 128;
  const int n_blk = blockIdx.x * 128;

  const int srow   = lane >> 3;
  const int schunk = (lane & 7) ^ (lane >> 3);   // XOR swizzle (row&7 == lane>>3)

  const bf16_t* Abase = A  + (size_t)m_blk * K;
  const bf16_t* Bbase = Bt + (size_t)n_blk * K;

  f32x4 acc[4][4] = {};

  for (int kk = 0; kk < K; kk += 64) {
    __syncthreads();
#pragma unroll
    for (int p = 0; p < 4; ++p) {
      int seg = w * 4 + p;
      int row = seg * 8 + srow;
      gl_lds16(Abase + (size_t)row * K + kk + schunk * 8, &sA[seg * 512]);
      gl_lds16(Bbase + (size_t)row * K + kk + schunk * 8, &sB[seg * 512]);
    }
    __syncthreads();
#pragma unroll
    for (int kc = 0; kc < 2; ++kc) {
      bf16x8 af[4], bfr[4];
      const int cs = (kc * 4 + quad) ^ (col & 7);
#pragma unroll
      for (int i = 0; i < 4; ++i) {
        af[i]  = *(const bf16x8*)&sA[(w_m + i * 16 + col) * 64 + cs * 8];
        bfr[i] = *(const bf16x8*)&sB[(w_n + i * 16 + col) * 64 + cs * 8];
      }
#pragma unroll
      for (int mi = 0; mi < 4; ++mi)
#pragma unroll
        for (int ni = 0; ni < 4; ++ni)
          acc[mi][ni] = mfma_bf16_32(af[mi], bfr[ni], acc[mi][ni]);
    }
  }

  const int sel = n_blk >> 11;   // block-uniform
  if (MODE == 0 && sel == 2) {
    // V: write packed PV fragments, one coalesced f16x4 store per (mi,ni)
#pragma unroll
    for (int mi = 0; mi < 4; ++mi)
#pragma unroll
      for (int ni = 0; ni < 4; ++ni) {
        int m0 = m_blk + w_m + mi * 16 + quad * 4;    // r=0 row
        int n  = n_blk + w_n + ni * 16 + col;
        int n_l = n & (H_ - 1);
        int head = n_l >> 7, hd = n_l & (HD_ - 1);
        int b = m0 >> 11, s0 = m0 & (S_ - 1);
        int bh = b * NH_ + head;
        int frag = (bh * 32 + (s0 >> 6)) * 32 + (hd >> 4) * 4 + ((s0 >> 4) & 3);
        int lane2 = ((s0 >> 2) & 3) * 16 + (hd & 15); // == quad*16+col
        f16x4 o;
#pragma unroll
        for (int r = 0; r < 4; ++r) o[r] = (f16_t)acc[mi][ni][r];
        *(f16x4*)&outV[(size_t)frag * 256 + lane2 * 4] = o;
      }
  } else {
#pragma unroll
    for (int mi = 0; mi < 4; ++mi)
#pragma unroll
      for (int ni = 0; ni < 4; ++ni)
#pragma unroll
        for (int r = 0; r < 4; ++r) {
          int m = m_blk + w_m + mi * 16 + quad * 4 + r;
          int n = n_blk + w_n + ni * 16 + col;
          float v = acc[mi][ni][r];
          if (MODE == 0) {
            int n_l = n & (H_ - 1);
            int head = n_l >> 7, hd = n_l & (HD_ - 1);
            int b = m >> 11, s = m & (S_ - 1);
            size_t idx = (((size_t)(b * NH_ + head)) * S_ + s) * HD_ + hd;
            if (sel == 0) outQ[idx] = (bf16_t)v;
            else          outK[idx] = (bf16_t)v;
          } else {
            outF[(size_t)m * H_ + n] = v;
          }
        }
  }
}

// ---------------- RoPE(Q in-place) + RoPE(K)+pack into MFMA A-fragment order ----
// Kp frag (bh, kt, t, kc): lane(col,quad) holds K[bh][kt*64+t*16+col][kc*32+quad*8..+7]
__global__ void rope_pack(bf16_t* __restrict__ Qb, const bf16_t* __restrict__ Kn,
                          bf16_t* __restrict__ Kp) {
  int i = blockIdx.x * 256 + threadIdx.x;   // 2 * 524288 threads
  int isK = i >> 19;
  int ii = i & 524287;
  int d8 = ii & 7;
  int s  = (ii >> 3) & (S_ - 1);
  int bh = ii >> 14;
  int d0 = d8 * 8;
  const bf16_t* row = (isK ? Kn : (const bf16_t*)Qb) + ((size_t)bh * S_ + s) * HD_;
  bf16x8 a = *(const bf16x8*)(row + d0);
  bf16x8 b = *(const bf16x8*)(row + d0 + 64);
  bf16x8 o1, o2;
#pragma unroll
  for (int j = 0; j < 8; ++j) {
    int d = d0 + j;
    float ang = (float)s * exp2f(-(float)d * (13.287712379549449f / 64.f));
    float c = cosf(ang), sn = sinf(ang);
    float x1 = (float)a[j], x2 = (float)b[j];
    o1[j] = (bf16_t)(x1 * c - x2 * sn);
    o2[j] = (bf16_t)(x2 * c + x1 * sn);
  }
  if (!isK) {
    bf16_t* wr = Qb + ((size_t)bh * S_ + s) * HD_;
    *(bf16x8*)(wr + d0)      = o1;
    *(bf16x8*)(wr + d0 + 64) = o2;
  } else {
    int kt = s >> 6, t = (s >> 4) & 3;
    int lane_ = (d8 & 3) * 16 + (s & 15);
    int kc1 = d0 >> 5;
    bf16_t* base = Kp + ((size_t)(bh * 32 + kt) * 16) * 512;
    *(bf16x8*)(base + (size_t)(t * 4 + kc1) * 512 + lane_ * 8)     = o1;
    *(bf16x8*)(base + (size_t)(t * 4 + kc1 + 2) * 512 + lane_ * 8) = o2;
  }
}

// ---------------- Flash causal attention: SINGLE-buffer K/V (32 KB LDS), 4 blk/CU --
// Per-tile split-wait pipeline:
//   QK(sK) | softmax | vmcnt(0) BAR(publish sV; sK dead) | stageK(kt+1) issued
//   PV(sV) | BAR | stageV(kt+1) issued, vmcnt(4)=K done (V crosses barrier in
//   flight) | BAR(publish sK).
// qt map: per-XCD balanced AND per-CU balanced (g2 rotation by y-octet).
// T13 defer-max (THR=8, log2 domain): skip the oacc rescale pass unless some
// row's max grew by >8; P values then bounded by 2^8=256 (safe in f16).
// launch_bounds (256,4): NOT 5 — oacc needs 32 AGPR + ~64 VGPR (unified file);
// budget at 5 waves/EU (~96-102) is right at the edge -> spill risk (r4 lesson).
__global__ __launch_bounds__(256, 4)
void flash_attn(const bf16_t* __restrict__ Q, const bf16_t* __restrict__ Kp,
                const f16_t* __restrict__ Vp, bf16_t* __restrict__ Out) {
  __shared__ bf16_t sK[8192];   // 16 KB
  __shared__ f16_t  sV[8192];   // 16 KB
  const int lane = threadIdx.x & 63;
  const int col  = lane & 15;
  const int quad = lane >> 4;
  const int w    = threadIdx.x >> 6;

  const int c = blockIdx.x & 7, g = blockIdx.x >> 3;
  const int g2 = (g + (blockIdx.y >> 3)) & 3;
  const int qt = (g2 == 0) ? c : (g2 == 1) ? 15 - c : (g2 == 2) ? 16 + c : 31 - c;
  const int bh = blockIdx.y;
  const int ktmax = qt;

  const bf16_t* KpB = Kp + (size_t)bh * 32 * 8192;
  const f16_t*  VpB = Vp + (size_t)bh * 32 * 8192;

  auto stageK = [&](int kt) {
#pragma unroll
    for (int r = 0; r < 4; ++r) {
      int seg = r * 4 + w;
      gl_lds16(KpB + (size_t)kt * 8192 + seg * 512 + lane * 8, &sK[seg * 512]);
    }
  };
  auto stageV = [&](int kt) {
#pragma unroll
    for (int r = 0; r < 4; ++r) {
      int seg = r * 4 + w;
      gl_lds16(VpB + (size_t)kt * 8192 + seg * 512 + lane * 8, &sV[seg * 512]);
    }
  };

  // Q fragments (16 q-rows/wave), pre-scaled by 1/sqrt(HD)*log2(e).
  // These normal loads are fully retired (compiler waitcnt before the scale
  // loop) BEFORE any gl_lds16 issues, so manual vmcnt counting stays exact.
  const float scale2 = 0.12751744154f;
  const bf16_t* Qrow = Q + ((size_t)bh * S_ + qt * 64 + w * 16 + col) * HD_;
  bf16x8 qf[4];
#pragma unroll
  for (int kc = 0; kc < 4; ++kc) {
    qf[kc] = *(const bf16x8*)(Qrow + kc * 32 + quad * 8);
#pragma unroll
    for (int j = 0; j < 8; ++j) qf[kc][j] = (bf16_t)((float)qf[kc][j] * scale2);
  }

  f32x4 oacc[8] = {};
  float m_i = -1e30f, l_i = 0.f;

  stageK(0);            // 4 loads
  stageV(0);            // 4 loads
  WAITCNT_VM(4)         // K0 done; V0 stays in flight across the barrier
  BARRIER();

  for (int kt = 0; kt <= ktmax; ++kt) {
    // St = K.Q^T (C-layout: col=q, quad*4+r=k)
    f32x4 st[4] = {};
    __builtin_amdgcn_s_setprio(1);
#pragma unroll
    for (int kc = 0; kc < 4; ++kc)
#pragma unroll
      for (int t = 0; t < 4; ++t) {
        bf16x8 kf = *(const bf16x8*)&sK[(t * 4 + kc) * 512 + lane * 8];
        st[t] = mfma_bf16_32(kf, qf[kc], st[t]);
      }
    __builtin_amdgcn_s_setprio(0);

    if (kt == ktmax) {           // diagonal tile: causal mask
      int ql = w * 16 + col;
#pragma unroll
      for (int t = 0; t < 4; ++t)
#pragma unroll
        for (int r = 0; r < 4; ++r)
          if (t * 16 + quad * 4 + r > ql) st[t][r] = -1e30f;
    }

    // online softmax (log2 domain), in-register over 16 + shfl(16,32)
    float mx = st[0][0];
#pragma unroll
    for (int t = 0; t < 4; ++t)
#pragma unroll
      for (int r = 0; r < 4; ++r) mx = fmaxf(mx, st[t][r]);
    mx = fmaxf(mx, __shfl_xor(mx, 16, 64));
    mx = fmaxf(mx, __shfl_xor(mx, 32, 64));
    // T13 defer-max: only rescale when some row's max grew past THR=8.
    if (__ballot(mx - m_i > 8.0f)) {
      float mn = fmaxf(m_i, mx);
      float alpha = exp2f(m_i - mn);
#pragma unroll
      for (int dt = 0; dt < 8; ++dt)
#pragma unroll
        for (int r = 0; r < 4; ++r) oacc[dt][r] *= alpha;
      l_i *= alpha;
      m_i = mn;
    }

    float sum = 0.f;
    f16x4 pf[4];
#pragma unroll
    for (int t = 0; t < 4; ++t)
#pragma unroll
      for (int r = 0; r < 4; ++r) {
        float pv = exp2f(st[t][r] - m_i);
        sum += pv;
        pf[t][r] = (f16_t)pv;
      }
    sum += __shfl_xor(sum, 16, 64);
    sum += __shfl_xor(sum, 32, 64);
    l_i += sum;

    WAITCNT_VM(0)        // own V-stage loads done (all else long retired)
    BARRIER();           // publish sV; also: all waves finished reading sK

    if (kt < ktmax) stageK(kt + 1);   // into sK, hides under PV

    // O^T += V^T.P^T  (P straight from registers; V frags contiguous/lane)
    __builtin_amdgcn_s_setprio(1);
#pragma unroll
    for (int t = 0; t < 4; ++t)
#pragma unroll
      for (int dt = 0; dt < 8; ++dt) {
        f16x4 vf = *(const f16x4*)&sV[(dt * 4 + t) * 256 + lane * 4];
        oacc[dt] = mfma_f16_16(vf, pf[t], oacc[dt]);
      }
    __builtin_amdgcn_s_setprio(0);

    if (kt < ktmax) {
      BARRIER();         // all waves finished reading sV
      stageV(kt + 1);    // into sV
      WAITCNT_VM(4)      // K(kt+1) done; V(kt+1) crosses barrier in flight
      BARRIER();         // publish sK(kt+1)
    }
  }

  float inv = 1.0f / l_i;
  int b = bh >> 4, h = bh & (NH_ - 1);
  int qg = qt * 64 + w * 16 + col;
  bf16_t* Orow = Out + ((size_t)b * S_ + qg) * H_ + h * HD_;
#pragma unroll
  for (int dt = 0; dt < 8; ++dt) {
    bf16x4 o4;
#pragma unroll
    for (int r = 0; r < 4; ++r) o4[r] = (bf16_t)(oacc[dt][r] * inv);
    *(bf16x4*)(Orow + dt * 16 + quad * 4) = o4;
  }
}

// ---------------- launch ----------------
extern "C" void kernel_launch(void* const* d_in, const int* in_sizes, int n_in,
                              void* d_out, int out_size, void* d_ws, size_t ws_size,
                              hipStream_t stream) {
  const float* hs = (const float*)d_in[0];
  // d_in[1] = attention_mask: exactly causal tril(0,-1e9) -> applied analytically
  const float* Wq = (const float*)d_in[2];
  const float* Wk = (const float*)d_in[3];
  const float* Wv = (const float*)d_in[4];
  const float* Wo = (const float*)d_in[5];
  float* out = (float*)d_out;

  char* ws = (char*)d_ws;
  size_t off = 0;
  auto alloc = [&](size_t bytes) -> void* {
    void* p = ws + off;
    off += (bytes + 255) & ~(size_t)255;
    return p;
  };
  bf16_t* hs_b  = (bf16_t*)alloc((size_t)M_ * H_ * 2);
  bf16_t* wqkv  = (bf16_t*)alloc((size_t)3 * H_ * H_ * 2);   // reused as Kp after GEMM
  bf16_t* wo_b  = (bf16_t*)alloc((size_t)H_ * H_ * 2);
  bf16_t* Qbuf  = (bf16_t*)alloc((size_t)M_ * H_ * 2);
  bf16_t* Kbuf  = (bf16_t*)alloc((size_t)M_ * H_ * 2);
  f16_t*  Vp    = (f16_t*)alloc((size_t)M_ * H_ * 2);        // packed PV fragments
  bf16_t* attn  = (bf16_t*)alloc((size_t)M_ * H_ * 2);

  cvt_all<<<24576, 256, 0, stream>>>(hs, Wq, Wk, Wv, Wo, hs_b, wqkv, wo_b);

  // fused QKV projection; V epilogue writes packed Vp directly
  gemm_mfma<0><<<dim3(48, 32), 256, 0, stream>>>(hs_b, wqkv, Qbuf, Kbuf,
                                                 Vp, nullptr, H_);

  bf16_t* Kp = wqkv;   // wqkv dead after GEMM
  rope_pack<<<4096, 256, 0, stream>>>(Qbuf, Kbuf, Kp);

  flash_attn<<<dim3(32, 32), 256, 0, stream>>>(Qbuf, Kp, Vp, attn);

  gemm_mfma<1><<<dim3(16, 32), 256, 0, stream>>>(attn, wo_b, nullptr, nullptr,
                                                 nullptr, out, H_);
}

// Round 6
// 368.053 us; speedup vs baseline: 1.7015x; 1.0361x over previous
//
#include <hip/hip_runtime.h>
#include <hip/hip_bf16.h>
#include <math.h>

#define B_  2
#define S_  2048
#define H_  2048
#define NH_ 16
#define HD_ 128
#define M_  (B_*S_)   // 4096

typedef __bf16 bf16_t;
typedef _Float16 f16_t;
typedef __bf16 bf16x8 __attribute__((ext_vector_type(8)));
typedef __bf16 bf16x4 __attribute__((ext_vector_type(4)));
typedef _Float16 f16x4 __attribute__((ext_vector_type(4)));
typedef float  f32x4  __attribute__((ext_vector_type(4)));

__device__ __forceinline__ f32x4 mfma_bf16_32(bf16x8 a, bf16x8 b, f32x4 c) {
  return __builtin_amdgcn_mfma_f32_16x16x32_bf16(a, b, c, 0, 0, 0);
}
__device__ __forceinline__ f32x4 mfma_f16_16(f16x4 a, f16x4 b, f32x4 c) {
  return __builtin_amdgcn_mfma_f32_16x16x16f16(a, b, c, 0, 0, 0);
}
__device__ __forceinline__ void gl_lds16(const void* g, void* l) {
  __builtin_amdgcn_global_load_lds((const __attribute__((address_space(1))) void*)g,
                                   (__attribute__((address_space(3))) void*)l, 16, 0, 0);
}
// s_waitcnt simm16 (gfx9): vmcnt[3:0] | expcnt(7=nowait)<<4 | lgkmcnt(15=nowait)<<8 | vmcnt[5:4]<<14
#define WAITCNT_VM(n) { asm volatile("" ::: "memory"); \
                        __builtin_amdgcn_s_waitcnt(((n) & 0xF) | 0x70 | 0xF00 | (((n) >> 4) << 14)); \
                        asm volatile("" ::: "memory"); }
#define BARRIER()     { asm volatile("" ::: "memory"); __builtin_amdgcn_s_barrier(); \
                        asm volatile("" ::: "memory"); }

// ---------------- all fp32 -> bf16 converts in one launch ----------------
__global__ void cvt_all(const float* __restrict__ hs, const float* __restrict__ wq,
                        const float* __restrict__ wk, const float* __restrict__ wv,
                        const float* __restrict__ wo, bf16_t* __restrict__ hs_b,
                        bf16_t* __restrict__ wqkv, bf16_t* __restrict__ wo_b) {
  int i = (blockIdx.x * 256 + threadIdx.x) * 4;   // element index (24M total)
  const float* src;
  bf16_t* dst;
  if (i < 8388608)        { src = hs + i;              dst = hs_b + i; }
  else if (i < 12582912)  { src = wq + (i - 8388608);  dst = wqkv + (i - 8388608); }
  else if (i < 16777216)  { src = wk + (i - 12582912); dst = wqkv + (i - 8388608); }
  else if (i < 20971520)  { src = wv + (i - 16777216); dst = wqkv + (i - 8388608); }
  else                    { src = wo + (i - 20971520); dst = wo_b + (i - 20971520); }
  float4 v = *(const float4*)src;
  bf16x4 o;
  o[0] = (bf16_t)v.x; o[1] = (bf16_t)v.y; o[2] = (bf16_t)v.z; o[3] = (bf16_t)v.w;
  *(bf16x4*)dst = o;
}

// ---------------- bf16 MFMA GEMM, global_load_lds + XOR-swizzled LDS ----------------
// MODE 0: fused QKV + RoPE epilogue (N=6144):
//   n<2048 -> Q: RoPE'd in-epilogue, written [B,NH,S,HD] bf16
//   n<4096 -> K: RoPE'd + packed directly into MFMA A-fragment order (Kp)
//   else   -> V: DIRECT-PACKED PV-fragment layout f16:
//             Vp[((bh*32+kt)*32 + (hd>>4)*4 + ((s>>4)&3))*256 + lane*4 + (s&3)]
// MODE 1: fp32 row-major [M, H_]
// launch_bounds (256,3): r4 falsified the "bound pins occupancy" theory —
// (256,5) forced the VGPR budget to ~96-102 while this kernel needs ~64 arch
// VGPR + 64 AGPR (unified file on gfx950) -> accumulator spill, WRITE_SIZE
// 49->664 MB, 3x slower. Keep budget at 3 waves/EU.
template<int MODE>
__global__ __launch_bounds__(256, 3)
void gemm_mfma(const bf16_t* __restrict__ A, const bf16_t* __restrict__ Bt,
               bf16_t* __restrict__ outQ, bf16_t* __restrict__ outK,
               f16_t* __restrict__ outV, float* __restrict__ outF, int K) {
  __shared__ bf16_t sS[128 * 128];        // 32 KB: staging (2x16KB) + rope stash
  bf16_t* const sA = sS;
  bf16_t* const sB = sS + 128 * 64;
  const int tid  = threadIdx.x;
  const int lane = tid & 63;
  const int w    = tid >> 6;
  const int col  = lane & 15;
  const int quad = lane >> 4;
  const int w_m  = (w & 1) * 64;
  const int w_n  = (w >> 1) * 64;
  const int m_blk = blockIdx.y * 128;
  const int n_blk = blockIdx.x * 128;

  const int srow   = lane >> 3;
  const int schunk = (lane & 7) ^ (lane >> 3);   // XOR swizzle (row&7 == lane>>3)

  const bf16_t* Abase = A  + (size_t)m_blk * K;
  const bf16_t* Bbase = Bt + (size_t)n_blk * K;

  f32x4 acc[4][4] = {};

  for (int kk = 0; kk < K; kk += 64) {
    __syncthreads();
#pragma unroll
    for (int p = 0; p < 4; ++p) {
      int seg = w * 4 + p;
      int row = seg * 8 + srow;
      gl_lds16(Abase + (size_t)row * K + kk + schunk * 8, &sA[seg * 512]);
      gl_lds16(Bbase + (size_t)row * K + kk + schunk * 8, &sB[seg * 512]);
    }
    __syncthreads();
#pragma unroll
    for (int kc = 0; kc < 2; ++kc) {
      bf16x8 af[4], bfr[4];
      const int cs = (kc * 4 + quad) ^ (col & 7);
#pragma unroll
      for (int i = 0; i < 4; ++i) {
        af[i]  = *(const bf16x8*)&sA[(w_m + i * 16 + col) * 64 + cs * 8];
        bfr[i] = *(const bf16x8*)&sB[(w_n + i * 16 + col) * 64 + cs * 8];
      }
#pragma unroll
      for (int mi = 0; mi < 4; ++mi)
#pragma unroll
        for (int ni = 0; ni < 4; ++ni)
          acc[mi][ni] = mfma_bf16_32(af[mi], bfr[ni], acc[mi][ni]);
    }
  }

  const int sel = n_blk >> 11;   // block-uniform
  if (MODE == 0 && sel == 2) {
    // V: write packed PV fragments, one coalesced f16x4 store per (mi,ni)
#pragma unroll
    for (int mi = 0; mi < 4; ++mi)
#pragma unroll
      for (int ni = 0; ni < 4; ++ni) {
        int m0 = m_blk + w_m + mi * 16 + quad * 4;    // r=0 row
        int n  = n_blk + w_n + ni * 16 + col;
        int n_l = n & (H_ - 1);
        int head = n_l >> 7, hd = n_l & (HD_ - 1);
        int b = m0 >> 11, s0 = m0 & (S_ - 1);
        int bh = b * NH_ + head;
        int frag = (bh * 32 + (s0 >> 6)) * 32 + (hd >> 4) * 4 + ((s0 >> 4) & 3);
        int lane2 = ((s0 >> 2) & 3) * 16 + (hd & 15); // == quad*16+col
        f16x4 o;
#pragma unroll
        for (int r = 0; r < 4; ++r) o[r] = (f16_t)acc[mi][ni][r];
        *(f16x4*)&outV[(size_t)frag * 256 + lane2 * 4] = o;
      }
  } else if (MODE == 0) {
    // Q/K: fused RoPE epilogue. Stash bf16 tile [128m][128n] into sS with
    // XOR-swizzle (ln ^= (lm&7)<<3; linear would be the 32-way G4 conflict
    // on the b128 re-reads), barrier, then 2 threads/row apply RoPE on
    // (hd, hd+64) pairs and write Q rows / packed-Kp fragments directly.
    // Numerics identical to the old rope_pack (RoPE on bf16-rounded output).
    __syncthreads();                 // all waves done reading sA/sB
#pragma unroll
    for (int mi = 0; mi < 4; ++mi)
#pragma unroll
      for (int ni = 0; ni < 4; ++ni) {
        int lm0 = w_m + mi * 16 + quad * 4;
        int ln  = w_n + ni * 16 + col;
#pragma unroll
        for (int r = 0; r < 4; ++r) {
          int lm = lm0 + r;
          sS[lm * 128 + (ln ^ ((lm & 7) << 3))] = (bf16_t)acc[mi][ni][r];
        }
      }
    __syncthreads();
    const int row  = tid >> 1;       // 0..127 local m
    const int half = tid & 1;        // d-range half*32 .. +31 (pairs with +64)
    const int m    = m_blk + row;
    const int b    = m >> 11, s = m & (S_ - 1);
    const int head = (n_blk & (H_ - 1)) >> 7;
    const int bh   = b * NH_ + head;
    const int swz  = (row & 7) << 3;
    const int kt = s >> 6, t = (s >> 4) & 3;
    bf16_t* qwr   = outQ + ((size_t)bh * S_ + s) * HD_ + half * 32;
    bf16_t* kbase = outK + ((size_t)(bh * 32 + kt) * 16) * 512;
#pragma unroll
    for (int k = 0; k < 4; ++k) {
      int e1 = row * 128 + ((half * 32 + k * 8) ^ swz);
      bf16x8 x1 = *(const bf16x8*)&sS[e1];
      bf16x8 x2 = *(const bf16x8*)&sS[e1 + 64];
      bf16x8 o1, o2;
#pragma unroll
      for (int j = 0; j < 8; ++j) {
        int d = half * 32 + k * 8 + j;
        float ang = (float)s * exp2f(-(float)d * (13.287712379549449f / 64.f));
        float cc, sn;
        sincosf(ang, &sn, &cc);
        float a1 = (float)x1[j], a2 = (float)x2[j];
        o1[j] = (bf16_t)(a1 * cc - a2 * sn);
        o2[j] = (bf16_t)(a2 * cc + a1 * sn);
      }
      if (sel == 0) {
        *(bf16x8*)(qwr + k * 8)      = o1;
        *(bf16x8*)(qwr + 64 + k * 8) = o2;
      } else {
        int lane_ = k * 16 + (s & 15);
        *(bf16x8*)(kbase + (size_t)(t * 4 + half) * 512 + lane_ * 8)     = o1;
        *(bf16x8*)(kbase + (size_t)(t * 4 + half + 2) * 512 + lane_ * 8) = o2;
      }
    }
  } else {
#pragma unroll
    for (int mi = 0; mi < 4; ++mi)
#pragma unroll
      for (int ni = 0; ni < 4; ++ni)
#pragma unroll
        for (int r = 0; r < 4; ++r) {
          int m = m_blk + w_m + mi * 16 + quad * 4 + r;
          int n = n_blk + w_n + ni * 16 + col;
          outF[(size_t)m * H_ + n] = acc[mi][ni][r];
        }
  }
}

// ---------------- Flash causal attention: SINGLE-buffer K/V (32 KB LDS), 4 blk/CU --
// Per-tile split-wait pipeline:
//   QK(sK) | softmax | vmcnt(0) BAR(publish sV; sK dead) | stageK(kt+1) issued
//   PV(sV) | BAR | stageV(kt+1) issued, vmcnt(4)=K done (V crosses barrier in
//   flight) | BAR(publish sK).
// qt map: per-XCD balanced AND per-CU balanced (g2 rotation by y-octet).
// T13 defer-max (THR=8, log2 domain): skip the oacc rescale pass unless some
// row's max grew by >8; P values then bounded by 2^8=256 (safe in f16).
// launch_bounds (256,4): NOT 5 — oacc needs 32 AGPR + ~64 VGPR (unified file);
// budget at 5 waves/EU (~96-102) is right at the edge -> spill risk (r4 lesson).
__global__ __launch_bounds__(256, 4)
void flash_attn(const bf16_t* __restrict__ Q, const bf16_t* __restrict__ Kp,
                const f16_t* __restrict__ Vp, bf16_t* __restrict__ Out) {
  __shared__ bf16_t sK[8192];   // 16 KB
  __shared__ f16_t  sV[8192];   // 16 KB
  const int lane = threadIdx.x & 63;
  const int col  = lane & 15;
  const int quad = lane >> 4;
  const int w    = threadIdx.x >> 6;

  const int c = blockIdx.x & 7, g = blockIdx.x >> 3;
  const int g2 = (g + (blockIdx.y >> 3)) & 3;
  const int qt = (g2 == 0) ? c : (g2 == 1) ? 15 - c : (g2 == 2) ? 16 + c : 31 - c;
  const int bh = blockIdx.y;
  const int ktmax = qt;

  const bf16_t* KpB = Kp + (size_t)bh * 32 * 8192;
  const f16_t*  VpB = Vp + (size_t)bh * 32 * 8192;

  auto stageK = [&](int kt) {
#pragma unroll
    for (int r = 0; r < 4; ++r) {
      int seg = r * 4 + w;
      gl_lds16(KpB + (size_t)kt * 8192 + seg * 512 + lane * 8, &sK[seg * 512]);
    }
  };
  auto stageV = [&](int kt) {
#pragma unroll
    for (int r = 0; r < 4; ++r) {
      int seg = r * 4 + w;
      gl_lds16(VpB + (size_t)kt * 8192 + seg * 512 + lane * 8, &sV[seg * 512]);
    }
  };

  // Q fragments (16 q-rows/wave), pre-scaled by 1/sqrt(HD)*log2(e).
  const float scale2 = 0.12751744154f;
  const bf16_t* Qrow = Q + ((size_t)bh * S_ + qt * 64 + w * 16 + col) * HD_;
  bf16x8 qf[4];
#pragma unroll
  for (int kc = 0; kc < 4; ++kc) {
    qf[kc] = *(const bf16x8*)(Qrow + kc * 32 + quad * 8);
#pragma unroll
    for (int j = 0; j < 8; ++j) qf[kc][j] = (bf16_t)((float)qf[kc][j] * scale2);
  }

  f32x4 oacc[8] = {};
  float m_i = -1e30f, l_i = 0.f;

  stageK(0);            // 4 loads
  stageV(0);            // 4 loads
  WAITCNT_VM(4)         // K0 done; V0 stays in flight across the barrier
  BARRIER();

  for (int kt = 0; kt <= ktmax; ++kt) {
    // St = K.Q^T (C-layout: col=q, quad*4+r=k)
    f32x4 st[4] = {};
    __builtin_amdgcn_s_setprio(1);
#pragma unroll
    for (int kc = 0; kc < 4; ++kc)
#pragma unroll
      for (int t = 0; t < 4; ++t) {
        bf16x8 kf = *(const bf16x8*)&sK[(t * 4 + kc) * 512 + lane * 8];
        st[t] = mfma_bf16_32(kf, qf[kc], st[t]);
      }
    __builtin_amdgcn_s_setprio(0);

    if (kt == ktmax) {           // diagonal tile: causal mask
      int ql = w * 16 + col;
#pragma unroll
      for (int t = 0; t < 4; ++t)
#pragma unroll
        for (int r = 0; r < 4; ++r)
          if (t * 16 + quad * 4 + r > ql) st[t][r] = -1e30f;
    }

    // online softmax (log2 domain), in-register over 16 + shfl(16,32)
    float mx = st[0][0];
#pragma unroll
    for (int t = 0; t < 4; ++t)
#pragma unroll
      for (int r = 0; r < 4; ++r) mx = fmaxf(mx, st[t][r]);
    mx = fmaxf(mx, __shfl_xor(mx, 16, 64));
    mx = fmaxf(mx, __shfl_xor(mx, 32, 64));
    // T13 defer-max: only rescale when some row's max grew past THR=8.
    if (__ballot(mx - m_i > 8.0f)) {
      float mn = fmaxf(m_i, mx);
      float alpha = exp2f(m_i - mn);
#pragma unroll
      for (int dt = 0; dt < 8; ++dt)
#pragma unroll
        for (int r = 0; r < 4; ++r) oacc[dt][r] *= alpha;
      l_i *= alpha;
      m_i = mn;
    }

    float sum = 0.f;
    f16x4 pf[4];
#pragma unroll
    for (int t = 0; t < 4; ++t)
#pragma unroll
      for (int r = 0; r < 4; ++r) {
        float pv = exp2f(st[t][r] - m_i);
        sum += pv;
        pf[t][r] = (f16_t)pv;
      }
    sum += __shfl_xor(sum, 16, 64);
    sum += __shfl_xor(sum, 32, 64);
    l_i += sum;

    WAITCNT_VM(0)        // own V-stage loads done (all else long retired)
    BARRIER();           // publish sV; also: all waves finished reading sK

    if (kt < ktmax) stageK(kt + 1);   // into sK, hides under PV

    // O^T += V^T.P^T  (P straight from registers; V frags contiguous/lane)
    __builtin_amdgcn_s_setprio(1);
#pragma unroll
    for (int t = 0; t < 4; ++t)
#pragma unroll
      for (int dt = 0; dt < 8; ++dt) {
        f16x4 vf = *(const f16x4*)&sV[(dt * 4 + t) * 256 + lane * 4];
        oacc[dt] = mfma_f16_16(vf, pf[t], oacc[dt]);
      }
    __builtin_amdgcn_s_setprio(0);

    if (kt < ktmax) {
      BARRIER();         // all waves finished reading sV
      stageV(kt + 1);    // into sV
      WAITCNT_VM(4)      // K(kt+1) done; V(kt+1) crosses barrier in flight
      BARRIER();         // publish sK(kt+1)
    }
  }

  float inv = 1.0f / l_i;
  int b = bh >> 4, h = bh & (NH_ - 1);
  int qg = qt * 64 + w * 16 + col;
  bf16_t* Orow = Out + ((size_t)b * S_ + qg) * H_ + h * HD_;
#pragma unroll
  for (int dt = 0; dt < 8; ++dt) {
    bf16x4 o4;
#pragma unroll
    for (int r = 0; r < 4; ++r) o4[r] = (bf16_t)(oacc[dt][r] * inv);
    *(bf16x4*)(Orow + dt * 16 + quad * 4) = o4;
  }
}

// ---------------- launch ----------------
extern "C" void kernel_launch(void* const* d_in, const int* in_sizes, int n_in,
                              void* d_out, int out_size, void* d_ws, size_t ws_size,
                              hipStream_t stream) {
  const float* hs = (const float*)d_in[0];
  // d_in[1] = attention_mask: exactly causal tril(0,-1e9) -> applied analytically
  const float* Wq = (const float*)d_in[2];
  const float* Wk = (const float*)d_in[3];
  const float* Wv = (const float*)d_in[4];
  const float* Wo = (const float*)d_in[5];
  float* out = (float*)d_out;

  char* ws = (char*)d_ws;
  size_t off = 0;
  auto alloc = [&](size_t bytes) -> void* {
    void* p = ws + off;
    off += (bytes + 255) & ~(size_t)255;
    return p;
  };
  bf16_t* hs_b  = (bf16_t*)alloc((size_t)M_ * H_ * 2);
  bf16_t* wqkv  = (bf16_t*)alloc((size_t)3 * H_ * H_ * 2);
  bf16_t* wo_b  = (bf16_t*)alloc((size_t)H_ * H_ * 2);
  bf16_t* Qbuf  = (bf16_t*)alloc((size_t)M_ * H_ * 2);
  bf16_t* Kp    = (bf16_t*)alloc((size_t)M_ * H_ * 2);       // packed rope'd K
  f16_t*  Vp    = (f16_t*)alloc((size_t)M_ * H_ * 2);        // packed PV fragments
  bf16_t* attn  = (bf16_t*)alloc((size_t)M_ * H_ * 2);

  cvt_all<<<24576, 256, 0, stream>>>(hs, Wq, Wk, Wv, Wo, hs_b, wqkv, wo_b);

  // fused QKV projection + RoPE epilogue: Q rope'd in [B,NH,S,HD], K rope'd
  // + packed into Kp, V packed into Vp. (Kp must NOT alias wqkv: the GEMM
  // reads weights while writing Kp.)
  gemm_mfma<0><<<dim3(48, 32), 256, 0, stream>>>(hs_b, wqkv, Qbuf, Kp,
                                                 Vp, nullptr, H_);

  flash_attn<<<dim3(32, 32), 256, 0, stream>>>(Qbuf, Kp, Vp, attn);

  gemm_mfma<1><<<dim3(16, 32), 256, 0, stream>>>(attn, wo_b, nullptr, nullptr,
                                                 nullptr, out, H_);
}